// Round 4
// baseline (23.420 us; speedup 1.0000x reference)
//
#include <hip/hip_runtime.h>
#include <math.h>

#define B_TOT 16384
#define F_SP  26
#define F_DN  13
#define VOCAB 100000
#define EMB   16

// ws layout: t_lin[B][8] fp32 partial first-order sums (512 KB).
#define WS_FLOATS (B_TOT * 8)

// ---------------- Kernel 1: lin partials with XCD-feature affinity ----------
// Group g = blockIdx%8 (XCD round-robin heuristic) owns features {g, g+8, g+16, g+24}.
// Each XCD's L2 only ever sees its ~1.2 MB slice of lin_emb hot lines -> the
// 2.8x within-replay line reuse becomes L2 hits, and slices persist across
// graph replays. Block = 4 waves x 64 samples; wave w handles feature g+8w.
__global__ __launch_bounds__(256) void lin_partial_kernel(
    const int*   __restrict__ sparse,    // [B, 26]
    const float* __restrict__ lin_emb,   // [26, 100000]
    float*       __restrict__ t_lin)     // [B][8]
{
    __shared__ int   s_idx[64 * F_SP];
    __shared__ float part[4][64];

    const int g     = blockIdx.x & 7;
    const int chunk = blockIdx.x >> 3;
    const int tid   = threadIdx.x;
    const int w     = tid >> 6;          // wave 0..3
    const int l     = tid & 63;
    const int b0    = chunk * 64;

    // Stage 64 samples' indices coalesced (6.6 KB).
    for (int i = tid; i < 64 * F_SP; i += 256)
        s_idx[i] = sparse[b0 * F_SP + i];
    __syncthreads();

    const int f = g + 8 * w;             // this wave's feature (invalid if >=26)
    float v = 0.f;
    if (f < F_SP) {
        const int idx = s_idx[l * F_SP + f];
        v = lin_emb[(size_t)f * VOCAB + (size_t)idx];
    }
    part[w][l] = v;
    __syncthreads();

    if (w == 0)
        t_lin[(size_t)(b0 + l) * 8 + g] =
            part[0][l] + part[1][l] + part[2][l] + part[3][l];
}

// ---------------- Kernel 2: fm gathers + combine + heads --------------------
// 16 threads/sample: d = g&7 (float2 dim chunk), fh = g>>3 (feature half).
__global__ __launch_bounds__(256) void fm_main_kernel(
    const int*   __restrict__ sparse,    // [B, 26]
    const float* __restrict__ dense,     // [B, 13]
    const float* __restrict__ ldW,       // [13]
    const float* __restrict__ ldB,       // [1]
    const float* __restrict__ fm_emb,    // [26, 100000, 16]
    const float* __restrict__ t_lin,     // [B][8]
    const float* __restrict__ fW, const float* __restrict__ fB,
    const float* __restrict__ lW, const float* __restrict__ lB,
    float*       __restrict__ out)       // [B, 2]
{
    __shared__ int s_idx[16 * F_SP];
    const int tid = threadIdx.x;
    const int block_base = blockIdx.x * 16;

    for (int i = tid; i < 16 * F_SP; i += 256)
        s_idx[i] = sparse[block_base * F_SP + i];
    __syncthreads();

    const int sloc = tid >> 4;
    const int g    = tid & 15;
    const int d    = g & 7;
    const int fh   = g >> 3;
    const int b    = block_base + sloc;
    const int* idx = &s_idx[sloc * F_SP];

    // First-order pieces: lanes 0..7 read this sample's 8 group partials
    // (contiguous 32B), lanes 0..12 add the dense dot terms.
    float lin = 0.f;
    if (g < 8)
        lin = t_lin[(size_t)b * 8 + g];
    if (g < F_DN)
        lin += dense[b * F_DN + g] * ldW[g];
    if (g == 0)
        lin += ldB[0];

    // Second-order: 13 independent float2 gathers per thread.
    float2 s = make_float2(0.f, 0.f);
    float ssq = 0.f;
    const int f0 = fh * 13;
    #pragma unroll
    for (int k = 0; k < 13; ++k) {
        const int f = f0 + k;
        const int v = idx[f];
        const float2 e = *reinterpret_cast<const float2*>(
            &fm_emb[((size_t)f * VOCAB + (size_t)v) * EMB + d * 2]);
        s.x += e.x; s.y += e.y;
        ssq += e.x * e.x + e.y * e.y;
    }

    s.x += __shfl_xor(s.x, 8);
    s.y += __shfl_xor(s.y, 8);

    const float p2 = s.x * s.x + s.y * s.y;
    float r = 0.25f * p2 - 0.5f * ssq + lin;
    r += __shfl_xor(r, 1);
    r += __shfl_xor(r, 2);
    r += __shfl_xor(r, 4);
    r += __shfl_xor(r, 8);

    if (g == 0) {
        const float finish = 1.f / (1.f + expf(-(r * fW[0] + fB[0])));
        const float like   = 1.f / (1.f + expf(-(r * lW[0] + lB[0])));
        *reinterpret_cast<float2*>(&out[b * 2]) = make_float2(finish, like);
    }
}

// ---------------- Fallback: round-2 single-pass kernel ----------------------
__global__ __launch_bounds__(256) void fm_mtl_kernel(
    const int*   __restrict__ sparse, const float* __restrict__ dense,
    const float* __restrict__ ldW, const float* __restrict__ ldB,
    const float* __restrict__ lin_emb, const float* __restrict__ fm_emb,
    const float* __restrict__ fW, const float* __restrict__ fB,
    const float* __restrict__ lW, const float* __restrict__ lB,
    float* __restrict__ out)
{
    __shared__ int s_idx[16 * F_SP];
    const int tid = threadIdx.x;
    const int block_base = blockIdx.x * 16;
    for (int i = tid; i < 16 * F_SP; i += 256)
        s_idx[i] = sparse[block_base * F_SP + i];
    __syncthreads();

    const int sloc = tid >> 4, g = tid & 15, d = g & 7, fh = g >> 3;
    const int b = block_base + sloc;
    const int* idx = &s_idx[sloc * F_SP];

    float lin = lin_emb[(size_t)g * VOCAB + (size_t)idx[g]];
    if (g < 10) lin += lin_emb[(size_t)(g + 16) * VOCAB + (size_t)idx[g + 16]];
    if (g < F_DN) lin += dense[b * F_DN + g] * ldW[g];
    if (g == 0) lin += ldB[0];

    float2 s = make_float2(0.f, 0.f);
    float ssq = 0.f;
    const int f0 = fh * 13;
    #pragma unroll
    for (int k = 0; k < 13; ++k) {
        const int f = f0 + k, v = idx[f];
        const float2 e = *reinterpret_cast<const float2*>(
            &fm_emb[((size_t)f * VOCAB + (size_t)v) * EMB + d * 2]);
        s.x += e.x; s.y += e.y;
        ssq += e.x * e.x + e.y * e.y;
    }
    s.x += __shfl_xor(s.x, 8);
    s.y += __shfl_xor(s.y, 8);
    const float p2 = s.x * s.x + s.y * s.y;
    float r = 0.25f * p2 - 0.5f * ssq + lin;
    r += __shfl_xor(r, 1); r += __shfl_xor(r, 2);
    r += __shfl_xor(r, 4); r += __shfl_xor(r, 8);
    if (g == 0) {
        const float finish = 1.f / (1.f + expf(-(r * fW[0] + fB[0])));
        const float like   = 1.f / (1.f + expf(-(r * lW[0] + lB[0])));
        *reinterpret_cast<float2*>(&out[b * 2]) = make_float2(finish, like);
    }
}

extern "C" void kernel_launch(void* const* d_in, const int* in_sizes, int n_in,
                              void* d_out, int out_size, void* d_ws, size_t ws_size,
                              hipStream_t stream) {
    const int*   sparse  = (const int*)  d_in[0];
    const float* dense   = (const float*)d_in[1];
    const float* ldW     = (const float*)d_in[2];
    const float* ldB     = (const float*)d_in[3];
    const float* lin_emb = (const float*)d_in[4];
    const float* fm_emb  = (const float*)d_in[5];
    const float* fW      = (const float*)d_in[6];
    const float* fB      = (const float*)d_in[7];
    const float* lW      = (const float*)d_in[8];
    const float* lB      = (const float*)d_in[9];
    float* out = (float*)d_out;

    if (ws_size >= (size_t)WS_FLOATS * sizeof(float)) {
        float* t_lin = (float*)d_ws;
        lin_partial_kernel<<<dim3(8 * (B_TOT / 64)), dim3(256), 0, stream>>>(
            sparse, lin_emb, t_lin);
        fm_main_kernel<<<dim3(B_TOT / 16), dim3(256), 0, stream>>>(
            sparse, dense, ldW, ldB, fm_emb, t_lin, fW, fB, lW, lB, out);
    } else {
        fm_mtl_kernel<<<dim3(B_TOT / 16), dim3(256), 0, stream>>>(
            sparse, dense, ldW, ldB, lin_emb, fm_emb, fW, fB, lW, lB, out);
    }
}

// Round 6
// 20.353 us; speedup vs baseline: 1.1507x; 1.1507x over previous
//
#include <hip/hip_runtime.h>
#include <math.h>

#define B_TOT 16384
#define F_SP  26
#define F_DN  13
#define VOCAB 100000
#define EMB   16

typedef float fvec2 __attribute__((ext_vector_type(2)));

// Single pass, 16 threads/sample (same structure as round-2 kernel).
// Change vs round 2: fm_emb gathers are NON-TEMPORAL (no L2 allocation) so the
// zero-reuse fm stream stops evicting the lin_emb hot lines (~2.9 MB/XCD,
// 2.6x reuse within a replay + full reuse across graph replays) from L2.
__global__ __launch_bounds__(256) void fm_mtl_kernel(
    const int*   __restrict__ sparse,    // [B, 26]
    const float* __restrict__ dense,     // [B, 13]
    const float* __restrict__ ldW,       // [13]
    const float* __restrict__ ldB,       // [1]
    const float* __restrict__ lin_emb,   // [26, 100000]
    const float* __restrict__ fm_emb,    // [26, 100000, 16]
    const float* __restrict__ fW, const float* __restrict__ fB,
    const float* __restrict__ lW, const float* __restrict__ lB,
    float*       __restrict__ out)       // [B, 2]
{
    __shared__ int s_idx[16 * F_SP];
    const int tid = threadIdx.x;
    const int block_base = blockIdx.x * 16;

    for (int i = tid; i < 16 * F_SP; i += 256)
        s_idx[i] = sparse[block_base * F_SP + i];
    __syncthreads();

    const int sloc = tid >> 4;   // sample within block
    const int g    = tid & 15;
    const int d    = g & 7;      // which float2 of the 16 emb dims
    const int fh   = g >> 3;     // which half of the 26 features
    const int b    = block_base + sloc;
    const int* idx = &s_idx[sloc * F_SP];

    // First-order gathers (normal loads -> allocate in L2; hot set persists).
    float lin = lin_emb[(size_t)g * VOCAB + (size_t)idx[g]];
    if (g < 10)
        lin += lin_emb[(size_t)(g + 16) * VOCAB + (size_t)idx[g + 16]];
    if (g < F_DN)
        lin += dense[b * F_DN + g] * ldW[g];
    if (g == 0)
        lin += ldB[0];

    // Second-order: 13 independent float2 gathers per thread, NON-TEMPORAL.
    fvec2 s = (fvec2)(0.f);
    float ssq = 0.f;
    const int f0 = fh * 13;
    #pragma unroll
    for (int k = 0; k < 13; ++k) {
        const int f = f0 + k;
        const int v = idx[f];
        const fvec2* ep = reinterpret_cast<const fvec2*>(
            &fm_emb[((size_t)f * VOCAB + (size_t)v) * EMB + d * 2]);
        const fvec2 e = __builtin_nontemporal_load(ep);
        s += e;
        ssq += e.x * e.x + e.y * e.y;
    }

    // Combine the two feature-halves of the summed vector (lane ^ 8).
    s.x += __shfl_xor(s.x, 8);
    s.y += __shfl_xor(s.y, 8);

    // Per-lane contribution; summed over the aligned 16-lane group:
    //   0.25*p2 twice per dim-lane -> 0.5 * sum_e s_e^2
    //   0.5*ssq disjoint           -> 0.5 * sum_{f,e} e^2
    //   lin/dense disjoint         -> full first-order
    const float p2 = s.x * s.x + s.y * s.y;
    float r = 0.25f * p2 - 0.5f * ssq + lin;
    r += __shfl_xor(r, 1);
    r += __shfl_xor(r, 2);
    r += __shfl_xor(r, 4);
    r += __shfl_xor(r, 8);

    if (g == 0) {
        const float finish = 1.f / (1.f + expf(-(r * fW[0] + fB[0])));
        const float like   = 1.f / (1.f + expf(-(r * lW[0] + lB[0])));
        *reinterpret_cast<float2*>(&out[b * 2]) = make_float2(finish, like);
    }
}

extern "C" void kernel_launch(void* const* d_in, const int* in_sizes, int n_in,
                              void* d_out, int out_size, void* d_ws, size_t ws_size,
                              hipStream_t stream) {
    const int*   sparse  = (const int*)  d_in[0];
    const float* dense   = (const float*)d_in[1];
    const float* ldW     = (const float*)d_in[2];
    const float* ldB     = (const float*)d_in[3];
    const float* lin_emb = (const float*)d_in[4];
    const float* fm_emb  = (const float*)d_in[5];
    const float* fW      = (const float*)d_in[6];
    const float* fB      = (const float*)d_in[7];
    const float* lW      = (const float*)d_in[8];
    const float* lB      = (const float*)d_in[9];
    float* out = (float*)d_out;

    fm_mtl_kernel<<<dim3(B_TOT / 16), dim3(256), 0, stream>>>(
        sparse, dense, ldW, ldB, lin_emb, fm_emb, fW, fB, lW, lB, out);
}